// Round 2
// baseline (8151.972 us; speedup 1.0000x reference)
//
#include <hip/hip_runtime.h>
#include <cstdint>
#include <cmath>

#define NN 8192
#define DD 512
#define KP1 31                      // k+1 with k=30
#define HALF_EDGES (NN * KP1)       // 253952

typedef float f2 __attribute__((ext_vector_type(2)));

// ---------------- Threefry-2x32-20, key = (0, 42) --------------------------
__device__ __forceinline__ uint32_t rotl32(uint32_t v, int s) {
  return (v << s) | (v >> (32 - s));
}

__device__ __forceinline__ void threefry2x32_42(uint32_t x0, uint32_t x1,
                                                uint32_t& o0, uint32_t& o1) {
  const uint32_t ks0 = 0u, ks1 = 42u;
  const uint32_t ks2 = 0x1BD11BDAu ^ ks0 ^ ks1;
  x0 += ks0; x1 += ks1;
  x0 += x1; x1 = rotl32(x1, 13); x1 ^= x0;
  x0 += x1; x1 = rotl32(x1, 15); x1 ^= x0;
  x0 += x1; x1 = rotl32(x1, 26); x1 ^= x0;
  x0 += x1; x1 = rotl32(x1, 6);  x1 ^= x0;
  x0 += ks1; x1 += ks2 + 1u;
  x0 += x1; x1 = rotl32(x1, 17); x1 ^= x0;
  x0 += x1; x1 = rotl32(x1, 29); x1 ^= x0;
  x0 += x1; x1 = rotl32(x1, 16); x1 ^= x0;
  x0 += x1; x1 = rotl32(x1, 24); x1 ^= x0;
  x0 += ks2; x1 += ks0 + 2u;
  x0 += x1; x1 = rotl32(x1, 13); x1 ^= x0;
  x0 += x1; x1 = rotl32(x1, 15); x1 ^= x0;
  x0 += x1; x1 = rotl32(x1, 26); x1 ^= x0;
  x0 += x1; x1 = rotl32(x1, 6);  x1 ^= x0;
  x0 += ks0; x1 += ks1 + 3u;
  x0 += x1; x1 = rotl32(x1, 17); x1 ^= x0;
  x0 += x1; x1 = rotl32(x1, 29); x1 ^= x0;
  x0 += x1; x1 = rotl32(x1, 16); x1 ^= x0;
  x0 += x1; x1 = rotl32(x1, 24); x1 ^= x0;
  x0 += ks1; x1 += ks2 + 4u;
  x0 += x1; x1 = rotl32(x1, 13); x1 ^= x0;
  x0 += x1; x1 = rotl32(x1, 15); x1 ^= x0;
  x0 += x1; x1 = rotl32(x1, 26); x1 ^= x0;
  x0 += x1; x1 = rotl32(x1, 6);  x1 ^= x0;
  x0 += ks2; x1 += ks0 + 5u;
  o0 = x0; o1 = x1;
}

__device__ __forceinline__ bool keep_edge(uint32_t e) {
  uint32_t y0, y1;
  threefry2x32_42(0u, e, y0, y1);
  uint32_t bits = y0 ^ y1;
  float u = __uint_as_float((bits >> 9) | 0x3f800000u) - 1.0f;
  return u < 0.9f;
}

// ---------------- K1: fp32 row norm (numpy pairwise tree) ------------------
__global__ __launch_bounds__(256) void rownorm_kernel(const float* __restrict__ x,
                                                      float* __restrict__ nrm) {
#pragma clang fp contract(off)
  __shared__ float rowbuf[16][DD];
  __shared__ float partial[16][4];
  int tid = threadIdx.x;
  int rowbase = blockIdx.x * 16;

  for (int p = 0; p < 8; ++p) {
    int f = tid + p * 256;
    int r = f >> 7, k4 = f & 127;
    *(float4*)(&rowbuf[r][k4 << 2]) =
        *(const float4*)(x + (size_t)(rowbase + r) * DD + (k4 << 2));
  }
  __syncthreads();
  if (tid < 64) {
    int r = tid >> 2, q = tid & 3;
    const float* s = &rowbuf[r][q * 128];
    float a0 = s[0]*s[0], a1 = s[1]*s[1], a2 = s[2]*s[2], a3 = s[3]*s[3];
    float a4 = s[4]*s[4], a5 = s[5]*s[5], a6 = s[6]*s[6], a7 = s[7]*s[7];
    for (int i = 8; i < 128; i += 8) {
      a0 += s[i+0]*s[i+0]; a1 += s[i+1]*s[i+1];
      a2 += s[i+2]*s[i+2]; a3 += s[i+3]*s[i+3];
      a4 += s[i+4]*s[i+4]; a5 += s[i+5]*s[i+5];
      a6 += s[i+6]*s[i+6]; a7 += s[i+7]*s[i+7];
    }
    partial[r][q] = ((a0 + a1) + (a2 + a3)) + ((a4 + a5) + (a6 + a7));
  }
  __syncthreads();
  if (tid < 16) {
    float S = (partial[tid][0] + partial[tid][1]) + (partial[tid][2] + partial[tid][3]);
    nrm[rowbase + tid] = sqrtf(S);
  }
}

// ---------------- K1b: xn = x / nrm (exact divide, done once) --------------
__global__ __launch_bounds__(256) void xnorm_kernel(const float* __restrict__ x,
                                                    const float* __restrict__ nrm,
                                                    float* __restrict__ xn) {
#pragma clang fp contract(off)
  int idx = blockIdx.x * 256 + threadIdx.x;   // float4 index, NN*128 total
  const float4* xv = (const float4*)x;
  float4* xo = (float4*)xn;
  float4 v = xv[idx];
  float n = nrm[idx >> 7];
  v.x = v.x / n; v.y = v.y / n; v.z = v.z / n; v.w = v.w / n;
  xo[idx] = v;
}

// ---------------- K2: upper-triangular 128x128 sim GEMM --------------------
// Static 32KB LDS, double-buffered BK=16 staging, ONE barrier per chunk.
// Per-element rounding contract: sequential separate mul+add, k ascending
// (bitwise-preserved; packed f2 ops are elementwise IEEE f32).
// LDS: As[2][128][4]f4 (slot-rotation (m + r>>3)&3) +
//      Bs[2][16][128]f (col XOR (k>>2)<<3). Staging writes 2-way uniform,
//      inner reads <=2-phase.
template <bool PRE>
__global__ __launch_bounds__(256, 4) void gemm_kernel(const float* __restrict__ x,
                                                      const float* __restrict__ nrm,
                                                      float* __restrict__ out) {
#pragma clang fp contract(off)
  // ---- triangular block index
  int bid = blockIdx.x;
  int by = (int)((129.0f - sqrtf(16641.0f - 8.0f * (float)bid)) * 0.5f);
  while (64 * by - (by * (by - 1)) / 2 > bid) --by;
  while (64 * (by + 1) - ((by + 1) * by) / 2 <= bid) ++by;
  const int bx = by + (bid - (64 * by - (by * (by - 1)) / 2));

  __shared__ __align__(16) char smem[32768];
  float4* AsF4 = (float4*)smem;            // [2][128][4] float4 = 16 KB
  float*  Bs   = (float*)(smem + 16384);   // [2][16][128] float = 16 KB

  const int tid = threadIdx.x;
  const int rb = by * 128;
  const int cb = bx * 128;
  const int m = tid & 3;        // k f4-slot within 16-k chunk
  const int g = tid >> 2;       // 0..63: staging row/col

  float nA[2], nB[2];
  if (!PRE) {
    nA[0] = nrm[rb + g]; nA[1] = nrm[rb + g + 64];
    nB[0] = nrm[cb + g]; nB[1] = nrm[cb + g + 64];
  }

  const int lane = tid & 63, wave = tid >> 6;
  const int wr = wave >> 1, wc = wave & 1;
  const int lr = lane >> 3, lc = lane & 7;
  const int r0 = wr * 64 + lr * 8;     // 8 thread rows: r0..r0+7
  const int c0 = wc * 64 + lc * 8;     // 8 thread cols: c0..c0+7
  const int r3 = r0 >> 3;

  f2 acc[8][4];                        // acc[i][jp] = cols (c0+2jp, c0+2jp+1)
  #pragma unroll
  for (int i = 0; i < 8; ++i)
    #pragma unroll
    for (int jp = 0; jp < 4; ++jp) { acc[i][jp].x = 0.f; acc[i][jp].y = 0.f; }

  const float4* xv = (const float4*)x;

  float4 ra[2], rbv[2];

  auto stage = [&](int nbuf) {
    float4* Ab = AsF4 + nbuf * 512;
    float*  Bb = Bs + nbuf * 2048;
    #pragma unroll
    for (int p = 0; p < 2; ++p) {
      int r = g + 64 * p;
      float4 va = ra[p];
      if (!PRE) {
        va.x = va.x / nA[p]; va.y = va.y / nA[p];
        va.z = va.z / nA[p]; va.w = va.w / nA[p];
      }
      Ab[r * 4 + ((m + (r >> 3)) & 3)] = va;
      float4 vb = rbv[p];
      if (!PRE) {
        vb.x = vb.x / nB[p]; vb.y = vb.y / nB[p];
        vb.z = vb.z / nB[p]; vb.w = vb.w / nB[p];
      }
      // k-major transpose: Bs[k][col ^ ((k>>2)<<3)], k = 4m+j
      float* bp = Bb + (4 * m) * 128 + (r ^ (m << 3));
      bp[0]   = vb.x;
      bp[128] = vb.y;
      bp[256] = vb.z;
      bp[384] = vb.w;
    }
  };

  // prologue: chunk 0 -> regs -> buf 0
  #pragma unroll
  for (int p = 0; p < 2; ++p) {
    ra[p]  = xv[(size_t)(rb + g + 64 * p) * 128 + m];
    rbv[p] = xv[(size_t)(cb + g + 64 * p) * 128 + m];
  }
  stage(0);
  __syncthreads();

  #pragma unroll 2
  for (int t = 0; t < 32; ++t) {
    const int buf = t & 1;
    if (t < 31) {                        // issue next-chunk loads (in flight
      #pragma unroll                     //  across the whole compute phase)
      for (int p = 0; p < 2; ++p) {
        ra[p]  = xv[(size_t)(rb + g + 64 * p) * 128 + (t + 1) * 4 + m];
        rbv[p] = xv[(size_t)(cb + g + 64 * p) * 128 + (t + 1) * 4 + m];
      }
    }
    const float4* Ab = AsF4 + buf * 512;
    const float*  Bb = Bs + buf * 2048;
    #pragma unroll
    for (int k4 = 0; k4 < 4; ++k4) {
      float4 av[8];
      const int tA = (k4 + r3) & 3;
      #pragma unroll
      for (int i = 0; i < 8; ++i) av[i] = Ab[(r0 + i) * 4 + tA];
      float4 b01[8];
      const int csw = c0 ^ (k4 << 3);
      #pragma unroll
      for (int kk = 0; kk < 4; ++kk) {
        const float* bp = Bb + (4 * k4 + kk) * 128 + csw;
        b01[2 * kk]     = *(const float4*)(bp);
        b01[2 * kk + 1] = *(const float4*)(bp + 4);
      }
      #pragma unroll
      for (int kk = 0; kk < 4; ++kk) {
        f2 bb0 = {b01[2 * kk].x,     b01[2 * kk].y};
        f2 bb1 = {b01[2 * kk].z,     b01[2 * kk].w};
        f2 bb2 = {b01[2 * kk + 1].x, b01[2 * kk + 1].y};
        f2 bb3 = {b01[2 * kk + 1].z, b01[2 * kk + 1].w};
        #pragma unroll
        for (int i = 0; i < 8; ++i) {
          float a = ((const float*)&av[i])[kk];
          f2 t0 = a * bb0;
          f2 t1 = a * bb1;
          f2 t2 = a * bb2;
          f2 t3 = a * bb3;
          acc[i][0] = acc[i][0] + t0;    // v_pk per-element IEEE: bitwise ==
          acc[i][1] = acc[i][1] + t1;    //   scalar mul-then-add chain
          acc[i][2] = acc[i][2] + t2;
          acc[i][3] = acc[i][3] + t3;
        }
      }
    }
    if (t < 31) stage(buf ^ 1);          // write idle buffer (no extra barrier)
    __syncthreads();
  }

  // ---- epilogue -----------------------------------------------------------
  float4* outv = (float4*)out;

  // straight tile: direct from registers (thread cols are contiguous)
  #pragma unroll
  for (int i = 0; i < 8; ++i) {
    #pragma unroll
    for (int h = 0; h < 2; ++h) {
      float4 o;
      o.x = acc[i][2 * h].x;     o.y = acc[i][2 * h].y;
      o.z = acc[i][2 * h + 1].x; o.w = acc[i][2 * h + 1].y;
      outv[(size_t)(rb + r0 + i) * 2048 + ((cb + c0) >> 2) + h] = o;
    }
  }

  // transposed mirror via LDS re-tile, 4 quarters of 32 rows (stride 130,
  // f2 stores -> 8B aligned, <=4-way); Cs (16.6KB) overlays staging buffers
  if (rb != cb) {
    float* Cs = (float*)smem;
    #pragma unroll 1
    for (int q = 0; q < 4; ++q) {
      __syncthreads();
      if (wr == (q >> 1) && (lr >> 2) == (q & 1)) {
        const int rB = (lr & 3) * 8;
        #pragma unroll
        for (int i = 0; i < 8; ++i) {
          #pragma unroll
          for (int jp = 0; jp < 4; ++jp)
            *(f2*)(Cs + (rB + i) * 130 + wc * 64 + lc * 8 + 2 * jp) = acc[i][jp];
        }
      }
      __syncthreads();
      #pragma unroll
      for (int q2 = 0; q2 < 4; ++q2) {
        int f = tid + q2 * 256;              // 0..1023
        int c = f >> 3, t4 = f & 7;          // col 0..127, 4-row group 0..7
        float4 o;
        o.x = Cs[(4 * t4 + 0) * 130 + c];
        o.y = Cs[(4 * t4 + 1) * 130 + c];
        o.z = Cs[(4 * t4 + 2) * 130 + c];
        o.w = Cs[(4 * t4 + 3) * 130 + c];
        outv[(size_t)(cb + c) * 2048 + ((rb + q * 32) >> 2) + t4] = o;
      }
    }
  }
}

// ---------------- K3: per-row top-31, lane-registered O(1) insertion -------
__global__ __launch_bounds__(256) void topk_kernel(const float* __restrict__ sim,
                                                   float* __restrict__ vals,
                                                   int* __restrict__ inds) {
  const int w = threadIdx.x >> 6;
  const int lane = threadIdx.x & 63;
  const int row = blockIdx.x * 4 + w;

  float kval = -1e30f;
  int   kidx = 0;
  float kmin = -1e30f;

  const float* srow = sim + (size_t)row * NN;
  for (int grp = 0; grp < NN / 64; ++grp) {
    float v = srow[grp * 64 + lane];
    unsigned long long mask = __ballot(v > kmin);
    while (mask) {
      int src = __builtin_ctzll(mask);
      mask &= mask - 1;
      float vv = __shfl(v, src, 64);          // wave-uniform candidate
      if (vv > kmin) {
        int cc = grp * 64 + src;
        unsigned long long ge = __ballot(kval >= vv) & 0x7FFFFFFFull;
        int pos = __popcll(ge);               // slots strictly before vv
        float upv = __shfl_up(kval, 1, 64);
        int   upi = __shfl_up(kidx, 1, 64);
        if (lane < KP1) {
          if (lane == pos) { kval = vv; kidx = cc; }
          else if (lane > pos) { kval = upv; kidx = upi; }
        }
        kmin = __shfl(kval, KP1 - 1, 64);
      }
    }
  }
  if (lane < KP1) {
    vals[(size_t)row * KP1 + lane] = kval;
    inds[row * KP1 + lane] = kidx;
  }
}

// ---------------- K4: degree mass (norm_row + norm_col) --------------------
__global__ __launch_bounds__(256) void norm_kernel(const float* __restrict__ vals,
                                                   const int* __restrict__ inds,
                                                   float* __restrict__ norm) {
  int i = blockIdx.x * blockDim.x + threadIdx.x;
  if (i >= NN) return;
  float s = 0.f;
  for (int t = 0; t < KP1; ++t) {
    float v = vals[i * KP1 + t];
    s += v;
    atomicAdd(&norm[inds[i * KP1 + t]], v);
  }
  atomicAdd(&norm[i], s);
}

// ---------------- K5: normalize + relu + threefry dropout + scatter --------
__global__ __launch_bounds__(256) void scatter_kernel(const float* __restrict__ vals,
                                                      const int* __restrict__ inds,
                                                      const float* __restrict__ norm,
                                                      float* __restrict__ out) {
  int e = blockIdx.x * blockDim.x + threadIdx.x;
  if (e >= HALF_EDGES) return;
  int i = e / KP1;
  int c = inds[e];
  float v = vals[e];
  float nv = v * (1.0f / sqrtf(norm[i])) * (1.0f / sqrtf(norm[c]));
  if (isnan(nv)) nv = 0.f;
  nv = fmaxf(nv, 0.f);
  float scaled = nv / 0.9f;
  if (keep_edge((uint32_t)e))
    atomicAdd(out + (size_t)i * NN + c, scaled);
  if (keep_edge((uint32_t)(e + HALF_EDGES)))
    atomicAdd(out + (size_t)c * NN + i, scaled);
}

// ---------------------------------------------------------------------------
extern "C" void kernel_launch(void* const* d_in, const int* in_sizes, int n_in,
                              void* d_out, int out_size, void* d_ws, size_t ws_size,
                              hipStream_t stream) {
  (void)in_sizes; (void)n_in;
  const float* x = (const float*)d_in[0];
  float* out = (float*)d_out;

  // ws layout: first 2 MiB exactly = nrm + vals + inds + norm (proven budget);
  // optional xn (16 MiB) appended only if the workspace is big enough.
  float* nrm  = (float*)d_ws;                  // 8192 floats
  float* vals = nrm + NN;                      // 253952 floats
  int*   inds = (int*)(vals + HALF_EDGES);     // 253952 ints
  float* norm = (float*)(inds + HALF_EDGES);   // 8192 floats
  float* xn   = (float*)((char*)d_ws + (size_t)(2 * 1024 * 1024));
  const bool pre = ws_size >= (size_t)(2 * 1024 * 1024) + (size_t)NN * DD * 4;

  hipLaunchKernelGGL(rownorm_kernel, dim3(NN / 16), dim3(256), 0, stream, x, nrm);
  // sims -> d_out (256 MB scratch, consumed by topk before the final memset)
  if (pre) {
    hipLaunchKernelGGL(xnorm_kernel, dim3(NN * DD / 4 / 256), dim3(256), 0, stream,
                       x, nrm, xn);
    hipLaunchKernelGGL((gemm_kernel<true>), dim3(2080), dim3(256), 0, stream,
                       xn, (const float*)nullptr, out);
  } else {
    hipLaunchKernelGGL((gemm_kernel<false>), dim3(2080), dim3(256), 0, stream,
                       x, nrm, out);
  }
  hipLaunchKernelGGL(topk_kernel, dim3(NN / 4), dim3(256), 0, stream,
                     out, vals, inds);
  hipMemsetAsync(norm, 0, NN * sizeof(float), stream);
  hipLaunchKernelGGL(norm_kernel, dim3((NN + 255) / 256), dim3(256), 0, stream,
                     vals, inds, norm);
  hipMemsetAsync(d_out, 0, (size_t)out_size * sizeof(float), stream);
  hipLaunchKernelGGL(scatter_kernel, dim3((HALF_EDGES + 255) / 256), dim3(256), 0, stream,
                     vals, inds, norm, out);
}

// Round 3
// 4424.178 us; speedup vs baseline: 1.8426x; 1.8426x over previous
//
#include <hip/hip_runtime.h>
#include <cstdint>
#include <cmath>

#define NN 8192
#define DD 512
#define KP1 31                      // k+1 with k=30
#define HALF_EDGES (NN * KP1)       // 253952

typedef float f2 __attribute__((ext_vector_type(2)));

// ---------------- Threefry-2x32-20, key = (0, 42) --------------------------
__device__ __forceinline__ uint32_t rotl32(uint32_t v, int s) {
  return (v << s) | (v >> (32 - s));
}

__device__ __forceinline__ void threefry2x32_42(uint32_t x0, uint32_t x1,
                                                uint32_t& o0, uint32_t& o1) {
  const uint32_t ks0 = 0u, ks1 = 42u;
  const uint32_t ks2 = 0x1BD11BDAu ^ ks0 ^ ks1;
  x0 += ks0; x1 += ks1;
  x0 += x1; x1 = rotl32(x1, 13); x1 ^= x0;
  x0 += x1; x1 = rotl32(x1, 15); x1 ^= x0;
  x0 += x1; x1 = rotl32(x1, 26); x1 ^= x0;
  x0 += x1; x1 = rotl32(x1, 6);  x1 ^= x0;
  x0 += ks1; x1 += ks2 + 1u;
  x0 += x1; x1 = rotl32(x1, 17); x1 ^= x0;
  x0 += x1; x1 = rotl32(x1, 29); x1 ^= x0;
  x0 += x1; x1 = rotl32(x1, 16); x1 ^= x0;
  x0 += x1; x1 = rotl32(x1, 24); x1 ^= x0;
  x0 += ks2; x1 += ks0 + 2u;
  x0 += x1; x1 = rotl32(x1, 13); x1 ^= x0;
  x0 += x1; x1 = rotl32(x1, 15); x1 ^= x0;
  x0 += x1; x1 = rotl32(x1, 26); x1 ^= x0;
  x0 += x1; x1 = rotl32(x1, 6);  x1 ^= x0;
  x0 += ks0; x1 += ks1 + 3u;
  x0 += x1; x1 = rotl32(x1, 17); x1 ^= x0;
  x0 += x1; x1 = rotl32(x1, 29); x1 ^= x0;
  x0 += x1; x1 = rotl32(x1, 16); x1 ^= x0;
  x0 += x1; x1 = rotl32(x1, 24); x1 ^= x0;
  x0 += ks1; x1 += ks2 + 4u;
  x0 += x1; x1 = rotl32(x1, 13); x1 ^= x0;
  x0 += x1; x1 = rotl32(x1, 15); x1 ^= x0;
  x0 += x1; x1 = rotl32(x1, 26); x1 ^= x0;
  x0 += x1; x1 = rotl32(x1, 6);  x1 ^= x0;
  x0 += ks2; x1 += ks0 + 5u;
  o0 = x0; o1 = x1;
}

__device__ __forceinline__ bool keep_edge(uint32_t e) {
  uint32_t y0, y1;
  threefry2x32_42(0u, e, y0, y1);
  uint32_t bits = y0 ^ y1;
  float u = __uint_as_float((bits >> 9) | 0x3f800000u) - 1.0f;
  return u < 0.9f;
}

// ---------------- K1: fp32 row norm (numpy pairwise tree) ------------------
__global__ __launch_bounds__(256) void rownorm_kernel(const float* __restrict__ x,
                                                      float* __restrict__ nrm) {
#pragma clang fp contract(off)
  __shared__ float rowbuf[16][DD];
  __shared__ float partial[16][4];
  int tid = threadIdx.x;
  int rowbase = blockIdx.x * 16;

  for (int p = 0; p < 8; ++p) {
    int f = tid + p * 256;
    int r = f >> 7, k4 = f & 127;
    *(float4*)(&rowbuf[r][k4 << 2]) =
        *(const float4*)(x + (size_t)(rowbase + r) * DD + (k4 << 2));
  }
  __syncthreads();
  if (tid < 64) {
    int r = tid >> 2, q = tid & 3;
    const float* s = &rowbuf[r][q * 128];
    float a0 = s[0]*s[0], a1 = s[1]*s[1], a2 = s[2]*s[2], a3 = s[3]*s[3];
    float a4 = s[4]*s[4], a5 = s[5]*s[5], a6 = s[6]*s[6], a7 = s[7]*s[7];
    for (int i = 8; i < 128; i += 8) {
      a0 += s[i+0]*s[i+0]; a1 += s[i+1]*s[i+1];
      a2 += s[i+2]*s[i+2]; a3 += s[i+3]*s[i+3];
      a4 += s[i+4]*s[i+4]; a5 += s[i+5]*s[i+5];
      a6 += s[i+6]*s[i+6]; a7 += s[i+7]*s[i+7];
    }
    partial[r][q] = ((a0 + a1) + (a2 + a3)) + ((a4 + a5) + (a6 + a7));
  }
  __syncthreads();
  if (tid < 16) {
    float S = (partial[tid][0] + partial[tid][1]) + (partial[tid][2] + partial[tid][3]);
    nrm[rowbase + tid] = sqrtf(S);
  }
}

// ---------------- K1b: xn = x / nrm (exact divide, done once) --------------
__global__ __launch_bounds__(256) void xnorm_kernel(const float* __restrict__ x,
                                                    const float* __restrict__ nrm,
                                                    float* __restrict__ xn) {
#pragma clang fp contract(off)
  int idx = blockIdx.x * 256 + threadIdx.x;   // float4 index, NN*128 total
  const float4* xv = (const float4*)x;
  float4* xo = (float4*)xn;
  float4 v = xv[idx];
  float n = nrm[idx >> 7];
  v.x = v.x / n; v.y = v.y / n; v.z = v.z / n; v.w = v.w / n;
  xo[idx] = v;
}

// ---------------- K2: upper-triangular 128x128 sim GEMM --------------------
// R1 inner loop (proven 104 VGPR) + BK=16 double-buffered static LDS (32KB)
// with ONE barrier per chunk: loads(t+1) -> compute(buf t) -> stage(buf t^1)
// -> barrier. LDS-write and global-load latency hide under the other
// buffer's compute. Per-element rounding contract preserved: sequential
// separate mul+add, k ascending (f2 ops are elementwise IEEE f32).
// NOTE: launch_bounds min-waves MUST stay 2 — (256,4) caps VGPR at ~64 and
// spills the 64-float accumulator to scratch (R2: 28GB scratch traffic).
template <bool PRE>
__global__ __launch_bounds__(256, 2) void gemm_kernel(const float* __restrict__ x,
                                                      const float* __restrict__ nrm,
                                                      float* __restrict__ out) {
#pragma clang fp contract(off)
  // ---- triangular block index
  int bid = blockIdx.x;
  int by = (int)((129.0f - sqrtf(16641.0f - 8.0f * (float)bid)) * 0.5f);
  while (64 * by - (by * (by - 1)) / 2 > bid) --by;
  while (64 * (by + 1) - ((by + 1) * by) / 2 <= bid) ++by;
  const int bx = by + (bid - (64 * by - (by * (by - 1)) / 2));

  __shared__ __align__(16) char smem[32768];
  float4* AsF4 = (float4*)smem;            // [2][128][4] float4 = 16 KB
  float*  Bs   = (float*)(smem + 16384);   // [2][16][128] float = 16 KB

  const int tid = threadIdx.x;
  const int rb = by * 128;
  const int cb = bx * 128;
  const int m = tid & 3;        // k f4-slot within 16-k chunk
  const int g = tid >> 2;       // 0..63: staging row/col

  float nA[2], nB[2];
  if (!PRE) {
    nA[0] = nrm[rb + g]; nA[1] = nrm[rb + g + 64];
    nB[0] = nrm[cb + g]; nB[1] = nrm[cb + g + 64];
  }

  const int lane = tid & 63, wave = tid >> 6;
  const int wr = wave >> 1, wc = wave & 1;
  const int lr = lane >> 3, lc = lane & 7;
  const int r0 = wr * 64 + lr * 8;     // 8 thread rows: r0..r0+7
  const int c0 = wc * 64 + lc * 8;     // 8 thread cols: c0..c0+7
  const int r3 = r0 >> 3;

  f2 acc[8][4];                        // acc[i][jp] = cols (c0+2jp, c0+2jp+1)
  #pragma unroll
  for (int i = 0; i < 8; ++i)
    #pragma unroll
    for (int jp = 0; jp < 4; ++jp) { acc[i][jp].x = 0.f; acc[i][jp].y = 0.f; }

  const float4* xv = (const float4*)x;

  float4 ra[2], rbv[2];

  // prologue: chunk 0 -> regs -> buf 0
  #pragma unroll
  for (int p = 0; p < 2; ++p) {
    ra[p]  = xv[(size_t)(rb + g + 64 * p) * 128 + m];
    rbv[p] = xv[(size_t)(cb + g + 64 * p) * 128 + m];
  }
  {
    #pragma unroll
    for (int p = 0; p < 2; ++p) {
      int r = g + 64 * p;
      float4 va = ra[p];
      if (!PRE) {
        va.x = va.x / nA[p]; va.y = va.y / nA[p];
        va.z = va.z / nA[p]; va.w = va.w / nA[p];
      }
      AsF4[r * 4 + ((m + (r >> 3)) & 3)] = va;
      float4 vb = rbv[p];
      if (!PRE) {
        vb.x = vb.x / nB[p]; vb.y = vb.y / nB[p];
        vb.z = vb.z / nB[p]; vb.w = vb.w / nB[p];
      }
      float* bp = Bs + (4 * m) * 128 + (r ^ (m << 3));
      bp[0]   = vb.x;
      bp[128] = vb.y;
      bp[256] = vb.z;
      bp[384] = vb.w;
    }
  }
  __syncthreads();

  #pragma unroll 2
  for (int t = 0; t < 32; ++t) {
    const int buf = t & 1;
    if (t < 31) {                        // issue next-chunk loads early
      #pragma unroll
      for (int p = 0; p < 2; ++p) {
        ra[p]  = xv[(size_t)(rb + g + 64 * p) * 128 + (t + 1) * 4 + m];
        rbv[p] = xv[(size_t)(cb + g + 64 * p) * 128 + (t + 1) * 4 + m];
      }
    }
    // ---- compute current buffer
    const float4* Ab = AsF4 + buf * 512;
    const float*  Bb = Bs + buf * 2048;
    #pragma unroll
    for (int k4 = 0; k4 < 4; ++k4) {
      float4 av[8];
      const int tA = (k4 + r3) & 3;
      #pragma unroll
      for (int i = 0; i < 8; ++i) av[i] = Ab[(r0 + i) * 4 + tA];
      float4 b01[8];
      const int csw = c0 ^ (k4 << 3);
      #pragma unroll
      for (int kk = 0; kk < 4; ++kk) {
        const float* bp = Bb + (4 * k4 + kk) * 128 + csw;
        b01[2 * kk]     = *(const float4*)(bp);
        b01[2 * kk + 1] = *(const float4*)(bp + 4);
      }
      #pragma unroll
      for (int kk = 0; kk < 4; ++kk) {
        f2 bb0 = {b01[2 * kk].x,     b01[2 * kk].y};
        f2 bb1 = {b01[2 * kk].z,     b01[2 * kk].w};
        f2 bb2 = {b01[2 * kk + 1].x, b01[2 * kk + 1].y};
        f2 bb3 = {b01[2 * kk + 1].z, b01[2 * kk + 1].w};
        #pragma unroll
        for (int i = 0; i < 8; ++i) {
          float a = ((const float*)&av[i])[kk];
          f2 t0 = a * bb0;
          f2 t1 = a * bb1;
          f2 t2 = a * bb2;
          f2 t3 = a * bb3;
          acc[i][0] = acc[i][0] + t0;    // elementwise IEEE: bitwise ==
          acc[i][1] = acc[i][1] + t1;    //   scalar mul-then-add chain
          acc[i][2] = acc[i][2] + t2;
          acc[i][3] = acc[i][3] + t3;
        }
      }
    }
    // ---- stage next chunk into the idle buffer (overlaps nothing it reads)
    if (t < 31) {
      float4* Aw = AsF4 + (buf ^ 1) * 512;
      float*  Bw = Bs + (buf ^ 1) * 2048;
      #pragma unroll
      for (int p = 0; p < 2; ++p) {
        int r = g + 64 * p;
        float4 va = ra[p];
        if (!PRE) {
          va.x = va.x / nA[p]; va.y = va.y / nA[p];
          va.z = va.z / nA[p]; va.w = va.w / nA[p];
        }
        Aw[r * 4 + ((m + (r >> 3)) & 3)] = va;
        float4 vb = rbv[p];
        if (!PRE) {
          vb.x = vb.x / nB[p]; vb.y = vb.y / nB[p];
          vb.z = vb.z / nB[p]; vb.w = vb.w / nB[p];
        }
        float* bp = Bw + (4 * m) * 128 + (r ^ (m << 3));
        bp[0]   = vb.x;
        bp[128] = vb.y;
        bp[256] = vb.z;
        bp[384] = vb.w;
      }
    }
    __syncthreads();
  }

  // ---- epilogue -----------------------------------------------------------
  float4* outv = (float4*)out;

  // straight tile: direct from registers (thread cols are contiguous)
  #pragma unroll
  for (int i = 0; i < 8; ++i) {
    #pragma unroll
    for (int h = 0; h < 2; ++h) {
      float4 o;
      o.x = acc[i][2 * h].x;     o.y = acc[i][2 * h].y;
      o.z = acc[i][2 * h + 1].x; o.w = acc[i][2 * h + 1].y;
      outv[(size_t)(rb + r0 + i) * 2048 + ((cb + c0) >> 2) + h] = o;
    }
  }

  // transposed mirror via LDS re-tile, 4 quarters of 32 rows (stride 130,
  // f2 stores -> 8B aligned); Cs (16.6KB) overlays staging buffers
  if (rb != cb) {
    float* Cs = (float*)smem;
    #pragma unroll 1
    for (int q = 0; q < 4; ++q) {
      __syncthreads();
      if (wr == (q >> 1) && (lr >> 2) == (q & 1)) {
        const int rB = (lr & 3) * 8;
        #pragma unroll
        for (int i = 0; i < 8; ++i) {
          #pragma unroll
          for (int jp = 0; jp < 4; ++jp)
            *(f2*)(Cs + (rB + i) * 130 + wc * 64 + lc * 8 + 2 * jp) = acc[i][jp];
        }
      }
      __syncthreads();
      #pragma unroll
      for (int q2 = 0; q2 < 4; ++q2) {
        int f = tid + q2 * 256;              // 0..1023
        int c = f >> 3, t4 = f & 7;          // col 0..127, 4-row group 0..7
        float4 o;
        o.x = Cs[(4 * t4 + 0) * 130 + c];
        o.y = Cs[(4 * t4 + 1) * 130 + c];
        o.z = Cs[(4 * t4 + 2) * 130 + c];
        o.w = Cs[(4 * t4 + 3) * 130 + c];
        outv[(size_t)(cb + c) * 2048 + ((rb + q * 32) >> 2) + t4] = o;
      }
    }
  }
}

// ---------------- K3: per-row top-31, lane-registered O(1) insertion -------
__global__ __launch_bounds__(256) void topk_kernel(const float* __restrict__ sim,
                                                   float* __restrict__ vals,
                                                   int* __restrict__ inds) {
  const int w = threadIdx.x >> 6;
  const int lane = threadIdx.x & 63;
  const int row = blockIdx.x * 4 + w;

  float kval = -1e30f;
  int   kidx = 0;
  float kmin = -1e30f;

  const float* srow = sim + (size_t)row * NN;
  for (int grp = 0; grp < NN / 64; ++grp) {
    float v = srow[grp * 64 + lane];
    unsigned long long mask = __ballot(v > kmin);
    while (mask) {
      int src = __builtin_ctzll(mask);
      mask &= mask - 1;
      float vv = __shfl(v, src, 64);          // wave-uniform candidate
      if (vv > kmin) {
        int cc = grp * 64 + src;
        unsigned long long ge = __ballot(kval >= vv) & 0x7FFFFFFFull;
        int pos = __popcll(ge);               // slots strictly before vv
        float upv = __shfl_up(kval, 1, 64);
        int   upi = __shfl_up(kidx, 1, 64);
        if (lane < KP1) {
          if (lane == pos) { kval = vv; kidx = cc; }
          else if (lane > pos) { kval = upv; kidx = upi; }
        }
        kmin = __shfl(kval, KP1 - 1, 64);
      }
    }
  }
  if (lane < KP1) {
    vals[(size_t)row * KP1 + lane] = kval;
    inds[row * KP1 + lane] = kidx;
  }
}

// ---------------- K4: degree mass (norm_row + norm_col) --------------------
__global__ __launch_bounds__(256) void norm_kernel(const float* __restrict__ vals,
                                                   const int* __restrict__ inds,
                                                   float* __restrict__ norm) {
  int i = blockIdx.x * blockDim.x + threadIdx.x;
  if (i >= NN) return;
  float s = 0.f;
  for (int t = 0; t < KP1; ++t) {
    float v = vals[i * KP1 + t];
    s += v;
    atomicAdd(&norm[inds[i * KP1 + t]], v);
  }
  atomicAdd(&norm[i], s);
}

// ---------------- K5: normalize + relu + threefry dropout + scatter --------
__global__ __launch_bounds__(256) void scatter_kernel(const float* __restrict__ vals,
                                                      const int* __restrict__ inds,
                                                      const float* __restrict__ norm,
                                                      float* __restrict__ out) {
  int e = blockIdx.x * blockDim.x + threadIdx.x;
  if (e >= HALF_EDGES) return;
  int i = e / KP1;
  int c = inds[e];
  float v = vals[e];
  float nv = v * (1.0f / sqrtf(norm[i])) * (1.0f / sqrtf(norm[c]));
  if (isnan(nv)) nv = 0.f;
  nv = fmaxf(nv, 0.f);
  float scaled = nv / 0.9f;
  if (keep_edge((uint32_t)e))
    atomicAdd(out + (size_t)i * NN + c, scaled);
  if (keep_edge((uint32_t)(e + HALF_EDGES)))
    atomicAdd(out + (size_t)c * NN + i, scaled);
}

// ---------------------------------------------------------------------------
extern "C" void kernel_launch(void* const* d_in, const int* in_sizes, int n_in,
                              void* d_out, int out_size, void* d_ws, size_t ws_size,
                              hipStream_t stream) {
  (void)in_sizes; (void)n_in;
  const float* x = (const float*)d_in[0];
  float* out = (float*)d_out;

  // ws layout: first 2 MiB exactly = nrm + vals + inds + norm (proven budget);
  // optional xn (16 MiB) appended only if the workspace is big enough.
  float* nrm  = (float*)d_ws;                  // 8192 floats
  float* vals = nrm + NN;                      // 253952 floats
  int*   inds = (int*)(vals + HALF_EDGES);     // 253952 ints
  float* norm = (float*)(inds + HALF_EDGES);   // 8192 floats
  float* xn   = (float*)((char*)d_ws + (size_t)(2 * 1024 * 1024));
  const bool pre = ws_size >= (size_t)(2 * 1024 * 1024) + (size_t)NN * DD * 4;

  hipLaunchKernelGGL(rownorm_kernel, dim3(NN / 16), dim3(256), 0, stream, x, nrm);
  // sims -> d_out (256 MB scratch, consumed by topk before the final memset)
  if (pre) {
    hipLaunchKernelGGL(xnorm_kernel, dim3(NN * DD / 4 / 256), dim3(256), 0, stream,
                       x, nrm, xn);
    hipLaunchKernelGGL((gemm_kernel<true>), dim3(2080), dim3(256), 0, stream,
                       xn, (const float*)nullptr, out);
  } else {
    hipLaunchKernelGGL((gemm_kernel<false>), dim3(2080), dim3(256), 0, stream,
                       x, nrm, out);
  }
  hipLaunchKernelGGL(topk_kernel, dim3(NN / 4), dim3(256), 0, stream,
                     out, vals, inds);
  hipMemsetAsync(norm, 0, NN * sizeof(float), stream);
  hipLaunchKernelGGL(norm_kernel, dim3((NN + 255) / 256), dim3(256), 0, stream,
                     vals, inds, norm);
  hipMemsetAsync(d_out, 0, (size_t)out_size * sizeof(float), stream);
  hipLaunchKernelGGL(scatter_kernel, dim3((HALF_EDGES + 255) / 256), dim3(256), 0, stream,
                     vals, inds, norm, out);
}

// Round 4
// 1111.467 us; speedup vs baseline: 7.3344x; 3.9805x over previous
//
#include <hip/hip_runtime.h>
#include <cstdint>
#include <cmath>

#define NN 8192
#define DD 512
#define KP1 31                      // k+1 with k=30
#define HALF_EDGES (NN * KP1)       // 253952

typedef float f2 __attribute__((ext_vector_type(2)));

// ---------------- Threefry-2x32-20, key = (0, 42) --------------------------
__device__ __forceinline__ uint32_t rotl32(uint32_t v, int s) {
  return (v << s) | (v >> (32 - s));
}

__device__ __forceinline__ void threefry2x32_42(uint32_t x0, uint32_t x1,
                                                uint32_t& o0, uint32_t& o1) {
  const uint32_t ks0 = 0u, ks1 = 42u;
  const uint32_t ks2 = 0x1BD11BDAu ^ ks0 ^ ks1;
  x0 += ks0; x1 += ks1;
  x0 += x1; x1 = rotl32(x1, 13); x1 ^= x0;
  x0 += x1; x1 = rotl32(x1, 15); x1 ^= x0;
  x0 += x1; x1 = rotl32(x1, 26); x1 ^= x0;
  x0 += x1; x1 = rotl32(x1, 6);  x1 ^= x0;
  x0 += ks1; x1 += ks2 + 1u;
  x0 += x1; x1 = rotl32(x1, 17); x1 ^= x0;
  x0 += x1; x1 = rotl32(x1, 29); x1 ^= x0;
  x0 += x1; x1 = rotl32(x1, 16); x1 ^= x0;
  x0 += x1; x1 = rotl32(x1, 24); x1 ^= x0;
  x0 += ks2; x1 += ks0 + 2u;
  x0 += x1; x1 = rotl32(x1, 13); x1 ^= x0;
  x0 += x1; x1 = rotl32(x1, 15); x1 ^= x0;
  x0 += x1; x1 = rotl32(x1, 26); x1 ^= x0;
  x0 += x1; x1 = rotl32(x1, 6);  x1 ^= x0;
  x0 += ks0; x1 += ks1 + 3u;
  x0 += x1; x1 = rotl32(x1, 17); x1 ^= x0;
  x0 += x1; x1 = rotl32(x1, 29); x1 ^= x0;
  x0 += x1; x1 = rotl32(x1, 16); x1 ^= x0;
  x0 += x1; x1 = rotl32(x1, 24); x1 ^= x0;
  x0 += ks1; x1 += ks2 + 4u;
  x0 += x1; x1 = rotl32(x1, 13); x1 ^= x0;
  x0 += x1; x1 = rotl32(x1, 15); x1 ^= x0;
  x0 += x1; x1 = rotl32(x1, 26); x1 ^= x0;
  x0 += x1; x1 = rotl32(x1, 6);  x1 ^= x0;
  x0 += ks2; x1 += ks0 + 5u;
  o0 = x0; o1 = x1;
}

__device__ __forceinline__ bool keep_edge(uint32_t e) {
  uint32_t y0, y1;
  threefry2x32_42(0u, e, y0, y1);
  uint32_t bits = y0 ^ y1;
  float u = __uint_as_float((bits >> 9) | 0x3f800000u) - 1.0f;
  return u < 0.9f;
}

// async global->LDS, 16B per lane; dest = wave-uniform base + lane*16
__device__ __forceinline__ void gll16(const float4* gsrc, void* lds) {
  __builtin_amdgcn_global_load_lds(
      (const __attribute__((address_space(1))) uint32_t*)gsrc,
      (__attribute__((address_space(3))) uint32_t*)lds, 16, 0, 0);
}

// ---------------- K1: fp32 row norm (numpy pairwise tree) ------------------
__global__ __launch_bounds__(256) void rownorm_kernel(const float* __restrict__ x,
                                                      float* __restrict__ nrm) {
#pragma clang fp contract(off)
  __shared__ float rowbuf[16][DD];
  __shared__ float partial[16][4];
  int tid = threadIdx.x;
  int rowbase = blockIdx.x * 16;

  for (int p = 0; p < 8; ++p) {
    int f = tid + p * 256;
    int r = f >> 7, k4 = f & 127;
    *(float4*)(&rowbuf[r][k4 << 2]) =
        *(const float4*)(x + (size_t)(rowbase + r) * DD + (k4 << 2));
  }
  __syncthreads();
  if (tid < 64) {
    int r = tid >> 2, q = tid & 3;
    const float* s = &rowbuf[r][q * 128];
    float a0 = s[0]*s[0], a1 = s[1]*s[1], a2 = s[2]*s[2], a3 = s[3]*s[3];
    float a4 = s[4]*s[4], a5 = s[5]*s[5], a6 = s[6]*s[6], a7 = s[7]*s[7];
    for (int i = 8; i < 128; i += 8) {
      a0 += s[i+0]*s[i+0]; a1 += s[i+1]*s[i+1];
      a2 += s[i+2]*s[i+2]; a3 += s[i+3]*s[i+3];
      a4 += s[i+4]*s[i+4]; a5 += s[i+5]*s[i+5];
      a6 += s[i+6]*s[i+6]; a7 += s[i+7]*s[i+7];
    }
    partial[r][q] = ((a0 + a1) + (a2 + a3)) + ((a4 + a5) + (a6 + a7));
  }
  __syncthreads();
  if (tid < 16) {
    float S = (partial[tid][0] + partial[tid][1]) + (partial[tid][2] + partial[tid][3]);
    nrm[rowbase + tid] = sqrtf(S);
  }
}

// ---------------- K1b: xn = x / nrm (exact divide, done once) --------------
__global__ __launch_bounds__(256) void xnorm_kernel(const float* __restrict__ x,
                                                    const float* __restrict__ nrm,
                                                    float* __restrict__ xn) {
#pragma clang fp contract(off)
  int idx = blockIdx.x * 256 + threadIdx.x;   // float4 index, NN*128 total
  const float4* xv = (const float4*)x;
  float4* xo = (float4*)xn;
  float4 v = xv[idx];
  float n = nrm[idx >> 7];
  v.x = v.x / n; v.y = v.y / n; v.z = v.z / n; v.w = v.w / n;
  xo[idx] = v;
}

// ---------------- K2a (PRE): 128x128 tri GEMM, gll-A + dbuf, 1 barrier -----
// BK=16, double-buffered 32KB static LDS. A staged by global_load_lds
// (linear dest, inverse-rotation-swizzled per-lane SOURCE; read applies the
// rotation -> both-sides-consistent). B staged via 8 regs + transposing
// scalar stores into the idle buffer. ONE __syncthreads per chunk: its
// implicit vmcnt(0)/lgkmcnt(0) drain is the completion guarantee for the
// async A-loads and the B-writes of the NEXT buffer.
// Register budget (cap 128 at (256,2)): acc 64 + av 32 + bb 8 + rbv 8 +
// addr ~10 = ~120. kk-split B loads keep b-frag live at 8 not 32.
// Per-element rounding contract preserved: sequential separate mul+add,
// k ascending (f2 ops are elementwise IEEE f32).
__global__ __launch_bounds__(256, 2) void gemm_kernel_pre(const float* __restrict__ x,
                                                          float* __restrict__ out) {
#pragma clang fp contract(off)
  // ---- triangular block index
  int bid = blockIdx.x;
  int by = (int)((129.0f - sqrtf(16641.0f - 8.0f * (float)bid)) * 0.5f);
  while (64 * by - (by * (by - 1)) / 2 > bid) --by;
  while (64 * (by + 1) - ((by + 1) * by) / 2 <= bid) ++by;
  const int bx = by + (bid - (64 * by - (by * (by - 1)) / 2));

  __shared__ __align__(16) char smem[32768];
  float4* AsF4 = (float4*)smem;            // [2][128][4] f4 (8KB/buf)
  float*  Bs   = (float*)(smem + 16384);   // [2][16][128] f (8KB/buf)

  const int tid = threadIdx.x;
  const int rb = by * 128;
  const int cb = bx * 128;
  const int m = tid & 3;        // B k f4-slot within 16-k chunk
  const int g = tid >> 2;       // 0..63: B staging col

  const int lane = tid & 63, wave = tid >> 6;
  const int wr = wave >> 1, wc = wave & 1;
  const int lr = lane >> 3, lc = lane & 7;
  const int r0 = wr * 64 + lr * 8;     // 8 thread rows
  const int c0 = wc * 64 + lc * 8;     // 8 thread cols
  const int r3 = r0 >> 3;

  f2 acc[8][4];                        // acc[i][jp] = cols (c0+2jp, c0+2jp+1)
  #pragma unroll
  for (int i = 0; i < 8; ++i)
    #pragma unroll
    for (int jp = 0; jp < 4; ++jp) { acc[i][jp].x = 0.f; acc[i][jp].y = 0.f; }

  const float4* xv = (const float4*)x;
  float4 rbv[2];                       // B chunk in flight (next chunk)

  // lane's two gll slots: fi = wave*128 + q*64 + lane -> (r = fi>>2, mp = fi&3)
  // source slot = (mp - (r>>3)) & 3  (inverse of read rotation (k4 + r>>3)&3)
  int gr[2], gs[2];
  #pragma unroll
  for (int q = 0; q < 2; ++q) {
    int fi = wave * 128 + q * 64 + lane;
    gr[q] = fi >> 2;
    gs[q] = ((fi & 3) - (gr[q] >> 3)) & 3;
  }

  auto stage_A = [&](int nbuf, int t) {
    #pragma unroll
    for (int q = 0; q < 2; ++q)
      gll16(xv + (size_t)(rb + gr[q]) * 128 + t * 4 + gs[q],
            (void*)(AsF4 + nbuf * 512 + wave * 128 + q * 64));
  };
  auto load_B = [&](int t) {
    #pragma unroll
    for (int p = 0; p < 2; ++p)
      rbv[p] = xv[(size_t)(cb + g + 64 * p) * 128 + t * 4 + m];
  };
  auto write_B = [&](int nbuf) {
    #pragma unroll
    for (int p = 0; p < 2; ++p) {
      int r = g + 64 * p;
      float* bp = Bs + nbuf * 2048 + (4 * m) * 128 + (r ^ (m << 3));
      bp[0]   = rbv[p].x;
      bp[128] = rbv[p].y;
      bp[256] = rbv[p].z;
      bp[384] = rbv[p].w;
    }
  };

  // prologue: chunk 0 -> buf 0; prefetch B chunk 1
  load_B(0);
  write_B(0);
  stage_A(0, 0);
  load_B(1);

  #pragma unroll 1
  for (int t = 0; t < 32; ++t) {
    const int buf = t & 1;
    __syncthreads();                 // drains A-gll + B-writes for buf
    if (t < 31) {
      stage_A(buf ^ 1, t + 1);       // async, lands by next barrier
      write_B(buf ^ 1);              // rbv holds chunk t+1
      if (t < 30) load_B(t + 2);     // in flight across compute
    }
    const float4* Ab = AsF4 + buf * 512;
    const float*  Bb = Bs + buf * 2048;
    #pragma unroll
    for (int k4 = 0; k4 < 4; ++k4) {
      float4 av[8];
      const int tA = (k4 + r3) & 3;
      #pragma unroll
      for (int i = 0; i < 8; ++i) av[i] = Ab[(r0 + i) * 4 + tA];
      const int csw = c0 ^ (k4 << 3);
      #pragma unroll
      for (int kk = 0; kk < 4; ++kk) {
        const float* bp = Bb + (4 * k4 + kk) * 128 + csw;
        float4 b0 = *(const float4*)(bp);
        float4 b1 = *(const float4*)(bp + 4);
        f2 bb0 = {b0.x, b0.y};
        f2 bb1 = {b0.z, b0.w};
        f2 bb2 = {b1.x, b1.y};
        f2 bb3 = {b1.z, b1.w};
        #pragma unroll
        for (int i = 0; i < 8; ++i) {
          float a = ((const float*)&av[i])[kk];
          f2 t0 = a * bb0;
          f2 t1 = a * bb1;
          f2 t2 = a * bb2;
          f2 t3 = a * bb3;
          acc[i][0] = acc[i][0] + t0;  // elementwise IEEE: bitwise ==
          acc[i][1] = acc[i][1] + t1;  //   scalar mul-then-add chain
          acc[i][2] = acc[i][2] + t2;
          acc[i][3] = acc[i][3] + t3;
        }
      }
    }
  }

  // ---- epilogue -----------------------------------------------------------
  float4* outv = (float4*)out;

  // straight tile: direct from registers (thread cols are contiguous)
  #pragma unroll
  for (int i = 0; i < 8; ++i) {
    #pragma unroll
    for (int h = 0; h < 2; ++h) {
      float4 o;
      o.x = acc[i][2 * h].x;     o.y = acc[i][2 * h].y;
      o.z = acc[i][2 * h + 1].x; o.w = acc[i][2 * h + 1].y;
      outv[(size_t)(rb + r0 + i) * 2048 + ((cb + c0) >> 2) + h] = o;
    }
  }

  // transposed mirror via LDS re-tile, 4 quarters of 32 rows (stride 130)
  if (rb != cb) {
    float* Cs = (float*)smem;
    #pragma unroll 1
    for (int q = 0; q < 4; ++q) {
      __syncthreads();
      if (wr == (q >> 1) && (lr >> 2) == (q & 1)) {
        const int rB = (lr & 3) * 8;
        #pragma unroll
        for (int i = 0; i < 8; ++i) {
          #pragma unroll
          for (int jp = 0; jp < 4; ++jp)
            *(f2*)(Cs + (rB + i) * 130 + wc * 64 + lc * 8 + 2 * jp) = acc[i][jp];
        }
      }
      __syncthreads();
      #pragma unroll
      for (int q2 = 0; q2 < 4; ++q2) {
        int f = tid + q2 * 256;              // 0..1023
        int c = f >> 3, t4 = f & 7;          // col 0..127, 4-row group 0..7
        float4 o;
        o.x = Cs[(4 * t4 + 0) * 130 + c];
        o.y = Cs[(4 * t4 + 1) * 130 + c];
        o.z = Cs[(4 * t4 + 2) * 130 + c];
        o.w = Cs[(4 * t4 + 3) * 130 + c];
        outv[(size_t)(cb + c) * 2048 + ((rb + q * 32) >> 2) + t4] = o;
      }
    }
  }
}

// ---------------- K2b (fallback, !PRE): R1-verbatim gemm (proven 750us) ----
__global__ __launch_bounds__(256, 2) void gemm_kernel_fb(const float* __restrict__ x,
                                                         const float* __restrict__ nrm,
                                                         float* __restrict__ out) {
#pragma clang fp contract(off)
  int bid = blockIdx.x;
  int by = (int)((129.0f - sqrtf(16641.0f - 8.0f * (float)bid)) * 0.5f);
  while (64 * by - (by * (by - 1)) / 2 > bid) --by;
  while (64 * (by + 1) - ((by + 1) * by) / 2 <= bid) ++by;
  const int bx = by + (bid - (64 * by - (by * (by - 1)) / 2));

  extern __shared__ char smem[];
  float4* AsF4 = (float4*)smem;            // [128][8] float4 = 16 KB
  float*  Bs   = (float*)(smem + 16384);   // [32][128] float = 16 KB

  const int tid = threadIdx.x;
  const int rb = by * 128;
  const int cb = bx * 128;
  const int m = tid & 7;
  const int g = tid >> 3;

  float nA[4], nB[4];
  #pragma unroll
  for (int p = 0; p < 4; ++p) {
    nA[p] = nrm[rb + g + 32 * p];
    nB[p] = nrm[cb + g + 32 * p];
  }

  const int lane = tid & 63, wave = tid >> 6;
  const int wr = wave >> 1, wc = wave & 1;
  const int lr = lane >> 3, lc = lane & 7;
  const int r0 = wr * 64 + lr * 8;
  const int c0 = wc * 64 + lc * 8;
  const int r3 = r0 >> 3;

  f2 acc[8][4];
  #pragma unroll
  for (int i = 0; i < 8; ++i)
    #pragma unroll
    for (int jp = 0; jp < 4; ++jp) { acc[i][jp].x = 0.f; acc[i][jp].y = 0.f; }

  const float4* xv = (const float4*)x;
  float4 ra[4], rbv[4];
  #pragma unroll
  for (int p = 0; p < 4; ++p) {
    int r = g + 32 * p;
    ra[p]  = xv[(size_t)(rb + r) * 128 + m];
    rbv[p] = xv[(size_t)(cb + r) * 128 + m];
  }

  for (int kc = 0; kc < 16; ++kc) {
    __syncthreads();
    #pragma unroll
    for (int p = 0; p < 4; ++p) {
      int r = g + 32 * p;
      float4 va = ra[p];
      va.x = va.x / nA[p]; va.y = va.y / nA[p];
      va.z = va.z / nA[p]; va.w = va.w / nA[p];
      AsF4[r * 8 + ((m + (r >> 3)) & 7)] = va;
      float4 vb = rbv[p];
      vb.x = vb.x / nB[p]; vb.y = vb.y / nB[p];
      vb.z = vb.z / nB[p]; vb.w = vb.w / nB[p];
      float* bp = Bs + (4 * m) * 128 + (r ^ (m << 3));
      bp[0]   = vb.x;
      bp[128] = vb.y;
      bp[256] = vb.z;
      bp[384] = vb.w;
    }
    __syncthreads();
    if (kc < 15) {
      #pragma unroll
      for (int p = 0; p < 4; ++p) {
        int r = g + 32 * p;
        ra[p]  = xv[(size_t)(rb + r) * 128 + (kc + 1) * 8 + m];
        rbv[p] = xv[(size_t)(cb + r) * 128 + (kc + 1) * 8 + m];
      }
    }

    #pragma unroll 2
    for (int k4 = 0; k4 < 8; ++k4) {
      float4 av[8];
      const int tA = (k4 + r3) & 7;
      #pragma unroll
      for (int i = 0; i < 8; ++i) av[i] = AsF4[(r0 + i) * 8 + tA];
      float4 b01[8];
      const int csw = c0 ^ (k4 << 3);
      #pragma unroll
      for (int kk = 0; kk < 4; ++kk) {
        const float* bp = Bs + (4 * k4 + kk) * 128 + csw;
        b01[2 * kk]     = *(const float4*)(bp);
        b01[2 * kk + 1] = *(const float4*)(bp + 4);
      }
      #pragma unroll
      for (int kk = 0; kk < 4; ++kk) {
        f2 bb0 = {b01[2 * kk].x,     b01[2 * kk].y};
        f2 bb1 = {b01[2 * kk].z,     b01[2 * kk].w};
        f2 bb2 = {b01[2 * kk + 1].x, b01[2 * kk + 1].y};
        f2 bb3 = {b01[2 * kk + 1].z, b01[2 * kk + 1].w};
        #pragma unroll
        for (int i = 0; i < 8; ++i) {
          float a = ((const float*)&av[i])[kk];
          f2 t0 = a * bb0;
          f2 t1 = a * bb1;
          f2 t2 = a * bb2;
          f2 t3 = a * bb3;
          acc[i][0] = acc[i][0] + t0;
          acc[i][1] = acc[i][1] + t1;
          acc[i][2] = acc[i][2] + t2;
          acc[i][3] = acc[i][3] + t3;
        }
      }
    }
  }

  float4* outv = (float4*)out;
  #pragma unroll
  for (int i = 0; i < 8; ++i) {
    #pragma unroll
    for (int h = 0; h < 2; ++h) {
      float4 o;
      o.x = acc[i][2 * h].x;     o.y = acc[i][2 * h].y;
      o.z = acc[i][2 * h + 1].x; o.w = acc[i][2 * h + 1].y;
      outv[(size_t)(rb + r0 + i) * 2048 + ((cb + c0) >> 2) + h] = o;
    }
  }
  if (rb != cb) {
    float* Cs = (float*)smem;
    #pragma unroll 1
    for (int q = 0; q < 4; ++q) {
      __syncthreads();
      if (wr == (q >> 1) && (lr >> 2) == (q & 1)) {
        const int rB = (lr & 3) * 8;
        #pragma unroll
        for (int i = 0; i < 8; ++i) {
          #pragma unroll
          for (int jp = 0; jp < 4; ++jp)
            *(f2*)(Cs + (rB + i) * 130 + wc * 64 + lc * 8 + 2 * jp) = acc[i][jp];
        }
      }
      __syncthreads();
      #pragma unroll
      for (int q2 = 0; q2 < 4; ++q2) {
        int f = tid + q2 * 256;
        int c = f >> 3, t4 = f & 7;
        float4 o;
        o.x = Cs[(4 * t4 + 0) * 130 + c];
        o.y = Cs[(4 * t4 + 1) * 130 + c];
        o.z = Cs[(4 * t4 + 2) * 130 + c];
        o.w = Cs[(4 * t4 + 3) * 130 + c];
        outv[(size_t)(cb + c) * 2048 + ((rb + q * 32) >> 2) + t4] = o;
      }
    }
  }
}

// ---------------- K3: per-row top-31, lane-registered O(1) insertion -------
__global__ __launch_bounds__(256) void topk_kernel(const float* __restrict__ sim,
                                                   float* __restrict__ vals,
                                                   int* __restrict__ inds) {
  const int w = threadIdx.x >> 6;
  const int lane = threadIdx.x & 63;
  const int row = blockIdx.x * 4 + w;

  float kval = -1e30f;
  int   kidx = 0;
  float kmin = -1e30f;

  const float* srow = sim + (size_t)row * NN;
  for (int grp = 0; grp < NN / 64; ++grp) {
    float v = srow[grp * 64 + lane];
    unsigned long long mask = __ballot(v > kmin);
    while (mask) {
      int src = __builtin_ctzll(mask);
      mask &= mask - 1;
      float vv = __shfl(v, src, 64);          // wave-uniform candidate
      if (vv > kmin) {
        int cc = grp * 64 + src;
        unsigned long long ge = __ballot(kval >= vv) & 0x7FFFFFFFull;
        int pos = __popcll(ge);               // slots strictly before vv
        float upv = __shfl_up(kval, 1, 64);
        int   upi = __shfl_up(kidx, 1, 64);
        if (lane < KP1) {
          if (lane == pos) { kval = vv; kidx = cc; }
          else if (lane > pos) { kval = upv; kidx = upi; }
        }
        kmin = __shfl(kval, KP1 - 1, 64);
      }
    }
  }
  if (lane < KP1) {
    vals[(size_t)row * KP1 + lane] = kval;
    inds[row * KP1 + lane] = kidx;
  }
}

// ---------------- K4: degree mass (norm_row + norm_col) --------------------
__global__ __launch_bounds__(256) void norm_kernel(const float* __restrict__ vals,
                                                   const int* __restrict__ inds,
                                                   float* __restrict__ norm) {
  int i = blockIdx.x * blockDim.x + threadIdx.x;
  if (i >= NN) return;
  float s = 0.f;
  for (int t = 0; t < KP1; ++t) {
    float v = vals[i * KP1 + t];
    s += v;
    atomicAdd(&norm[inds[i * KP1 + t]], v);
  }
  atomicAdd(&norm[i], s);
}

// ---------------- K5: normalize + relu + threefry dropout + scatter --------
__global__ __launch_bounds__(256) void scatter_kernel(const float* __restrict__ vals,
                                                      const int* __restrict__ inds,
                                                      const float* __restrict__ norm,
                                                      float* __restrict__ out) {
  int e = blockIdx.x * blockDim.x + threadIdx.x;
  if (e >= HALF_EDGES) return;
  int i = e / KP1;
  int c = inds[e];
  float v = vals[e];
  float nv = v * (1.0f / sqrtf(norm[i])) * (1.0f / sqrtf(norm[c]));
  if (isnan(nv)) nv = 0.f;
  nv = fmaxf(nv, 0.f);
  float scaled = nv / 0.9f;
  if (keep_edge((uint32_t)e))
    atomicAdd(out + (size_t)i * NN + c, scaled);
  if (keep_edge((uint32_t)(e + HALF_EDGES)))
    atomicAdd(out + (size_t)c * NN + i, scaled);
}

// ---------------------------------------------------------------------------
extern "C" void kernel_launch(void* const* d_in, const int* in_sizes, int n_in,
                              void* d_out, int out_size, void* d_ws, size_t ws_size,
                              hipStream_t stream) {
  (void)in_sizes; (void)n_in;
  const float* x = (const float*)d_in[0];
  float* out = (float*)d_out;

  // ws layout: first 2 MiB exactly = nrm + vals + inds + norm (proven budget);
  // optional xn (16 MiB) appended only if the workspace is big enough.
  float* nrm  = (float*)d_ws;                  // 8192 floats
  float* vals = nrm + NN;                      // 253952 floats
  int*   inds = (int*)(vals + HALF_EDGES);     // 253952 ints
  float* norm = (float*)(inds + HALF_EDGES);   // 8192 floats
  float* xn   = (float*)((char*)d_ws + (size_t)(2 * 1024 * 1024));
  const bool pre = ws_size >= (size_t)(2 * 1024 * 1024) + (size_t)NN * DD * 4;

  hipLaunchKernelGGL(rownorm_kernel, dim3(NN / 16), dim3(256), 0, stream, x, nrm);
  // sims -> d_out (256 MB scratch, consumed by topk before the final memset)
  if (pre) {
    hipLaunchKernelGGL(xnorm_kernel, dim3(NN * DD / 4 / 256), dim3(256), 0, stream,
                       x, nrm, xn);
    hipLaunchKernelGGL(gemm_kernel_pre, dim3(2080), dim3(256), 0, stream,
                       xn, out);
  } else {
    hipLaunchKernelGGL(gemm_kernel_fb, dim3(2080), dim3(256), 32768, stream,
                       x, nrm, out);
  }
  hipLaunchKernelGGL(topk_kernel, dim3(NN / 4), dim3(256), 0, stream,
                     out, vals, inds);
  hipMemsetAsync(norm, 0, NN * sizeof(float), stream);
  hipLaunchKernelGGL(norm_kernel, dim3((NN + 255) / 256), dim3(256), 0, stream,
                     vals, inds, norm);
  hipMemsetAsync(d_out, 0, (size_t)out_size * sizeof(float), stream);
  hipLaunchKernelGGL(scatter_kernel, dim3((HALF_EDGES + 255) / 256), dim3(256), 0, stream,
                     vals, inds, norm, out);
}